// Round 1
// baseline (217.578 us; speedup 1.0000x reference)
//
#include <hip/hip_runtime.h>

// Net: x[B,2] -> fc1(2->9)+ELU -> 19 x (9->9)+ELU -> fc21(9->2) -> log_softmax
// B = 2097152 rows. All fp32. Compute-bound on the vector ALU (no fp32 MFMA).
//
// Strategy: one thread processes RPT=4 consecutive rows. All weight loads are
// wave-uniform -> compiler scalarizes to s_load, weights live in SGPRs and feed
// v_fmac_f32 directly. 9x9 inner loops fully unrolled; layer loop kept rolled
// to bound code size. ELU branchless: max(v, exp(min(v,0))-1)  (e^x-1 >= x).

constexpr int H    = 9;
constexpr int NMID = 19;
constexpr int RPT  = 4;   // rows per thread: amortizes 1746 uniform weight loads
constexpr int BLK  = 256;

__device__ __forceinline__ float elu_f(float v) {
    float t = fminf(v, 0.0f);
    float e = __expf(t);        // v_mul (log2e) + v_exp_f32
    return fmaxf(v, e - 1.0f);  // for v>0: e-1 == 0 <= v ; for v<=0: e-1 >= v
}

__global__ __launch_bounds__(BLK) void mlp_fused_kernel(
    const float* __restrict__ x,
    const float* __restrict__ W1,
    const float* __restrict__ b1,
    const float* __restrict__ Wmid,
    const float* __restrict__ bmid,
    const float* __restrict__ W21,
    const float* __restrict__ b21,
    float* __restrict__ out)
{
    const int t = blockIdx.x * BLK + threadIdx.x;
    const long long row0 = (long long)t * RPT;

    // Load 4 rows of x: 8 consecutive floats -> two float4 (coalesced 32B/lane)
    const float4* xv = (const float4*)(x + row0 * 2);
    float4 xa = xv[0];
    float4 xb = xv[1];
    float xin[RPT][2] = {{xa.x, xa.y}, {xa.z, xa.w}, {xb.x, xb.y}, {xb.z, xb.w}};

    float h[RPT][H];

    // ---- fc1: 2 -> 9, ELU ----
    #pragma unroll
    for (int j = 0; j < H; ++j) {
        const float w0 = W1[j * 2 + 0];
        const float w1 = W1[j * 2 + 1];
        const float bj = b1[j];
        #pragma unroll
        for (int r = 0; r < RPT; ++r) {
            float v = fmaf(xin[r][1], w1, bj);
            v = fmaf(xin[r][0], w0, v);
            h[r][j] = elu_f(v);
        }
    }

    // ---- fc2..fc20: 19 x (9 -> 9), ELU ----
    #pragma unroll 1
    for (int l = 0; l < NMID; ++l) {
        const float* __restrict__ W  = Wmid + l * (H * H);
        const float* __restrict__ bb = bmid + l * H;
        float hn[RPT][H];
        #pragma unroll
        for (int j = 0; j < H; ++j) {
            const float bj = bb[j];
            float acc[RPT];
            #pragma unroll
            for (int r = 0; r < RPT; ++r) acc[r] = bj;
            #pragma unroll
            for (int k = 0; k < H; ++k) {
                const float w = W[j * H + k];
                #pragma unroll
                for (int r = 0; r < RPT; ++r) acc[r] = fmaf(h[r][k], w, acc[r]);
            }
            #pragma unroll
            for (int r = 0; r < RPT; ++r) hn[r][j] = elu_f(acc[r]);
        }
        #pragma unroll
        for (int j = 0; j < H; ++j)
            #pragma unroll
            for (int r = 0; r < RPT; ++r) h[r][j] = hn[r][j];
    }

    // ---- fc21: 9 -> 2, then log_softmax over the 2 logits ----
    float o[RPT][2];
    const float c0 = b21[0];
    const float c1 = b21[1];
    #pragma unroll
    for (int r = 0; r < RPT; ++r) {
        float l0 = c0, l1 = c1;
        #pragma unroll
        for (int k = 0; k < H; ++k) {
            l0 = fmaf(h[r][k], W21[k],     l0);
            l1 = fmaf(h[r][k], W21[H + k], l1);
        }
        float m  = fmaxf(l0, l1);
        float e0 = __expf(l0 - m);
        float e1 = __expf(l1 - m);
        float lse = m + __logf(e0 + e1);
        o[r][0] = l0 - lse;
        o[r][1] = l1 - lse;
    }

    // Store 4 rows x 2 logprobs = 8 consecutive floats (two float4)
    float4* ov = (float4*)(out + row0 * 2);
    ov[0] = make_float4(o[0][0], o[0][1], o[1][0], o[1][1]);
    ov[1] = make_float4(o[2][0], o[2][1], o[3][0], o[3][1]);
}

extern "C" void kernel_launch(void* const* d_in, const int* in_sizes, int n_in,
                              void* d_out, int out_size, void* d_ws, size_t ws_size,
                              hipStream_t stream) {
    const float* x    = (const float*)d_in[0];
    const float* W1   = (const float*)d_in[1];
    const float* b1   = (const float*)d_in[2];
    const float* Wmid = (const float*)d_in[3];
    const float* bmid = (const float*)d_in[4];
    const float* W21  = (const float*)d_in[5];
    const float* b21  = (const float*)d_in[6];
    float* out = (float*)d_out;

    const int nrows = in_sizes[0] / 2;            // 2097152
    const int blocks = nrows / (BLK * RPT);       // 2048
    mlp_fused_kernel<<<blocks, BLK, 0, stream>>>(x, W1, b1, Wmid, bmid, W21, b21, out);
}